// Round 1
// baseline (26.441 us; speedup 1.0000x reference)
//
#include <hip/hip_runtime.h>
#include <math.h>

#define NLAYERS 2

// Kernel 1: compute the 8 (layer,wire) Rot gates from params (24 floats).
// gate g (= layer*4+wire): [g00, g01, g10, g11] complex, stored as 8 floats.
__global__ void compute_gates_kernel(const float* __restrict__ params,
                                     float* __restrict__ gates) {
    int g = threadIdx.x;
    if (g >= NLAYERS * 4) return;
    float phi   = params[g * 3 + 0];
    float theta = params[g * 3 + 1];
    float omega = params[g * 3 + 2];
    float ct, st, ca, sa, cb, sb;
    __sincosf(0.5f * theta, &st, &ct);
    __sincosf(0.5f * (phi + omega), &sa, &ca);
    __sincosf(0.5f * (phi - omega), &sb, &cb);
    // g00 = exp(-i*(phi+omega)/2)*ct ; g01 = -exp(i*(phi-omega)/2)*st
    // g10 = exp(-i*(phi-omega)/2)*st ; g11 = exp(i*(phi+omega)/2)*ct
    float* G = gates + g * 8;
    G[0] =  ca * ct;  G[1] = -sa * ct;   // g00 r,i
    G[2] = -cb * st;  G[3] = -sb * st;   // g01 r,i
    G[4] =  cb * st;  G[5] = -sb * st;   // g10 r,i
    G[6] =  ca * ct;  G[7] =  sa * ct;   // g11 r,i
}

// Kernel 2: one block per image. Threads 0..195 each simulate one 2x2 patch
// (4-qubit circuit, state in registers), write 4 feats to LDS; then all 256
// threads do the 784x10 head + log_softmax.
__global__ __launch_bounds__(256) void quanv_head_kernel(
    const float* __restrict__ x,        // (B, 784) image pixels
    const float* __restrict__ gatesg,   // 64 floats
    const float* __restrict__ head_w,   // (10, 784)
    const float* __restrict__ head_b,   // (10,)
    float* __restrict__ out,            // (B, 10)
    int B)
{
    __shared__ float gates[64];
    __shared__ float feats[784];
    __shared__ float red[10][4];
    __shared__ float logits_s[10];

    const int tid = threadIdx.x;
    const int b   = blockIdx.x;

    if (tid < 64) gates[tid] = gatesg[tid];
    __syncthreads();

    if (tid < 196) {
        const int pi_ = tid / 14, pj = tid % 14;
        const float* img = x + (size_t)b * 784;
        const float a0 = img[(2 * pi_)     * 28 + 2 * pj];
        const float a1 = img[(2 * pi_)     * 28 + 2 * pj + 1];
        const float a2 = img[(2 * pi_ + 1) * 28 + 2 * pj];
        const float a3 = img[(2 * pi_ + 1) * 28 + 2 * pj + 1];

        // Initial RY layer on |0000>: product state of [cos(a/2), sin(a/2)]
        float c0, s0, c1, s1, c2, s2, c3, s3;
        __sincosf(0.5f * a0, &s0, &c0);
        __sincosf(0.5f * a1, &s1, &c1);
        __sincosf(0.5f * a2, &s2, &c2);
        __sincosf(0.5f * a3, &s3, &c3);

        // State: index s = b0*8 + b1*4 + b2*2 + b3 (wire w -> bit 3-w)
        float pr[16], pim[16];
#pragma unroll
        for (int t = 0; t < 16; t++) {
            pr[t] = ((t & 8) ? s0 : c0) * ((t & 4) ? s1 : c1) *
                    ((t & 2) ? s2 : c2) * ((t & 1) ? s3 : c3);
            pim[t] = 0.0f;
        }

#define APPLY_ROT(LAYER, W)                                                   \
        {                                                                     \
            const float* G = &gates[((LAYER) * 4 + (W)) * 8];                 \
            const float g00r = G[0], g00i = G[1], g01r = G[2], g01i = G[3];   \
            const float g10r = G[4], g10i = G[5], g11r = G[6], g11i = G[7];   \
            const int str = 8 >> (W);                                         \
            _Pragma("unroll")                                                 \
            for (int t = 0; t < 16; t++) {                                    \
                if (t & str) continue;                                        \
                const int u = t | str;                                        \
                const float r0 = pr[t], i0 = pim[t];                          \
                const float r1 = pr[u], i1 = pim[u];                          \
                pr[t]  = g00r * r0 - g00i * i0 + g01r * r1 - g01i * i1;       \
                pim[t] = g00r * i0 + g00i * r0 + g01r * i1 + g01i * r1;       \
                pr[u]  = g10r * r0 - g10i * i0 + g11r * r1 - g11i * i1;       \
                pim[u] = g10r * i0 + g10i * r0 + g11r * i1 + g11i * r1;       \
            }                                                                 \
        }

#define APPLY_CNOT(C, T)                                                      \
        {                                                                     \
            const int cm = 8 >> (C), tm = 8 >> (T);                           \
            _Pragma("unroll")                                                 \
            for (int t = 0; t < 16; t++) {                                    \
                if ((t & cm) && !(t & tm)) {                                  \
                    const int u = t | tm;                                     \
                    float tr = pr[t];  pr[t]  = pr[u];  pr[u]  = tr;          \
                    float ti = pim[t]; pim[t] = pim[u]; pim[u] = ti;          \
                }                                                             \
            }                                                                 \
        }

        APPLY_ROT(0, 0) APPLY_ROT(0, 1) APPLY_ROT(0, 2) APPLY_ROT(0, 3)
        APPLY_CNOT(0, 1) APPLY_CNOT(2, 3) APPLY_CNOT(1, 2)
        APPLY_ROT(1, 0) APPLY_ROT(1, 1) APPLY_ROT(1, 2) APPLY_ROT(1, 3)
        APPLY_CNOT(0, 1) APPLY_CNOT(2, 3) APPLY_CNOT(1, 2)

        float m[16];
#pragma unroll
        for (int t = 0; t < 16; t++) m[t] = pr[t] * pr[t] + pim[t] * pim[t];

        float z0 = 0.f, z1 = 0.f, z2 = 0.f, z3 = 0.f;
#pragma unroll
        for (int t = 0; t < 16; t++) {
            z0 += (t & 8) ? -m[t] : m[t];
            z1 += (t & 4) ? -m[t] : m[t];
            z2 += (t & 2) ? -m[t] : m[t];
            z3 += (t & 1) ? -m[t] : m[t];
        }
        feats[tid * 4 + 0] = z0;
        feats[tid * 4 + 1] = z1;
        feats[tid * 4 + 2] = z2;
        feats[tid * 4 + 3] = z3;
    }
    __syncthreads();

    // Head: logits[k] = sum_j feats[j] * head_w[k*784+j] + head_b[k]
    float acc[10];
#pragma unroll
    for (int k = 0; k < 10; k++) acc[k] = 0.0f;
    for (int j = tid; j < 784; j += 256) {
        const float f = feats[j];
#pragma unroll
        for (int k = 0; k < 10; k++) acc[k] += f * head_w[k * 784 + j];
    }
    const int lane = tid & 63, wid = tid >> 6;
#pragma unroll
    for (int k = 0; k < 10; k++) {
        float v = acc[k];
#pragma unroll
        for (int off = 32; off > 0; off >>= 1) v += __shfl_down(v, off, 64);
        if (lane == 0) red[k][wid] = v;
    }
    __syncthreads();
    if (tid < 10) {
        logits_s[tid] = red[tid][0] + red[tid][1] + red[tid][2] + red[tid][3]
                        + head_b[tid];
    }
    __syncthreads();
    if (tid == 0) {
        float mx = logits_s[0];
#pragma unroll
        for (int k = 1; k < 10; k++) mx = fmaxf(mx, logits_s[k]);
        float sum = 0.0f;
#pragma unroll
        for (int k = 0; k < 10; k++) sum += __expf(logits_s[k] - mx);
        const float lse = __logf(sum);
        float* o = out + (size_t)b * 10;
#pragma unroll
        for (int k = 0; k < 10; k++) o[k] = logits_s[k] - mx - lse;
    }
}

extern "C" void kernel_launch(void* const* d_in, const int* in_sizes, int n_in,
                              void* d_out, int out_size, void* d_ws, size_t ws_size,
                              hipStream_t stream) {
    const float* x      = (const float*)d_in[0];
    const float* params = (const float*)d_in[1];
    const float* head_w = (const float*)d_in[2];
    const float* head_b = (const float*)d_in[3];
    float* out = (float*)d_out;
    float* gates = (float*)d_ws;   // 64 floats

    const int B = in_sizes[0] / 784;

    compute_gates_kernel<<<1, 64, 0, stream>>>(params, gates);
    quanv_head_kernel<<<B, 256, 0, stream>>>(x, gates, head_w, head_b, out, B);
}

// Round 2
// 15.843 us; speedup vs baseline: 1.6689x; 1.6689x over previous
//
#include <hip/hip_runtime.h>
#include <math.h>

// Complex helpers (r,i as separate floats)
#define CMUL_R(xr,xi,yr,yi) ((xr)*(yr) - (xi)*(yi))
#define CMUL_I(xr,xi,yr,yi) ((xr)*(yi) + (xi)*(yr))

// One block per image. Threads 0..7 compute the 8 Rot gates from params.
// Threads 0..195 each simulate one 2x2 patch (4-qubit circuit) using the
// factored product-state formulation; feats -> LDS; then 784x10 head +
// log_softmax in-block.
__global__ __launch_bounds__(256) void quanv_fused_kernel(
    const float* __restrict__ x,        // (B, 784)
    const float* __restrict__ params,   // (2,4,3) = 24 floats
    const float* __restrict__ head_w,   // (10, 784)
    const float* __restrict__ head_b,   // (10,)
    float* __restrict__ out,            // (B, 10)
    int B)
{
    __shared__ float gates[64];         // 8 gates x [g00r,g00i,g01r,g01i,g10r,g10i,g11r,g11i]
    __shared__ float feats[784];
    __shared__ float red[10][4];
    __shared__ float logits_s[10];

    const int tid = threadIdx.x;
    const int b   = blockIdx.x;

    if (tid < 8) {
        const float phi   = params[tid * 3 + 0];
        const float theta = params[tid * 3 + 1];
        const float omega = params[tid * 3 + 2];
        float ct, st, ca, sa, cb, sb;
        __sincosf(0.5f * theta,         &st, &ct);
        __sincosf(0.5f * (phi + omega), &sa, &ca);
        __sincosf(0.5f * (phi - omega), &sb, &cb);
        float* G = &gates[tid * 8];
        G[0] =  ca * ct;  G[1] = -sa * ct;   // g00
        G[2] = -cb * st;  G[3] = -sb * st;   // g01
        G[4] =  cb * st;  G[5] = -sb * st;   // g10
        G[6] =  ca * ct;  G[7] =  sa * ct;   // g11
    }
    __syncthreads();

    if (tid < 196) {
        const int pi_ = tid / 14, pj = tid % 14;
        const float* img = x + (size_t)b * 784;
        const float2 row0 = *(const float2*)(img + (2 * pi_)     * 28 + 2 * pj);
        const float2 row1 = *(const float2*)(img + (2 * pi_ + 1) * 28 + 2 * pj);
        const float a[4] = { row0.x, row0.y, row1.x, row1.y };

        // RY(a_w) on |0>: per-wire real state (c,s)
        float cw[4], sw[4];
#pragma unroll
        for (int w = 0; w < 4; w++) __sincosf(0.5f * a[w], &sw[w], &cw[w]);

        // Layer-0 Rot per wire (gate w): psi_w = G * (c,s), still product state
        float p0r[4], p0i[4], p1r[4], p1i[4];
#pragma unroll
        for (int w = 0; w < 4; w++) {
            const float g00r = gates[w*8+0], g00i = gates[w*8+1];
            const float g01r = gates[w*8+2], g01i = gates[w*8+3];
            const float g10r = gates[w*8+4], g10i = gates[w*8+5];
            const float g11r = gates[w*8+6], g11i = gates[w*8+7];
            p0r[w] = g00r * cw[w] + g01r * sw[w];
            p0i[w] = g00i * cw[w] + g01i * sw[w];
            p1r[w] = g10r * cw[w] + g11r * sw[w];
            p1i[w] = g10i * cw[w] + g11i * sw[w];
        }

        // Pair A(q0,q1) = psi0 (x) psi1, with CNOT(0,1) folded in (swap A[2]<->A[3])
        float Ar[4], Ai[4];
        Ar[0] = CMUL_R(p0r[0],p0i[0], p0r[1],p0i[1]); Ai[0] = CMUL_I(p0r[0],p0i[0], p0r[1],p0i[1]);
        Ar[1] = CMUL_R(p0r[0],p0i[0], p1r[1],p1i[1]); Ai[1] = CMUL_I(p0r[0],p0i[0], p1r[1],p1i[1]);
        Ar[2] = CMUL_R(p1r[0],p1i[0], p1r[1],p1i[1]); Ai[2] = CMUL_I(p1r[0],p1i[0], p1r[1],p1i[1]); // s1 swapped
        Ar[3] = CMUL_R(p1r[0],p1i[0], p0r[1],p0i[1]); Ai[3] = CMUL_I(p1r[0],p1i[0], p0r[1],p0i[1]);

        // Pair B(q2,q3) = psi2 (x) psi3, with CNOT(2,3) folded in (swap B[2]<->B[3])
        float Br[4], Bi[4];
        Br[0] = CMUL_R(p0r[2],p0i[2], p0r[3],p0i[3]); Bi[0] = CMUL_I(p0r[2],p0i[2], p0r[3],p0i[3]);
        Br[1] = CMUL_R(p0r[2],p0i[2], p1r[3],p1i[3]); Bi[1] = CMUL_I(p0r[2],p0i[2], p1r[3],p1i[3]);
        Br[2] = CMUL_R(p1r[2],p1i[2], p1r[3],p1i[3]); Bi[2] = CMUL_I(p1r[2],p1i[2], p1r[3],p1i[3]);
        Br[3] = CMUL_R(p1r[2],p1i[2], p0r[3],p0i[3]); Bi[3] = CMUL_I(p1r[2],p1i[2], p0r[3],p0i[3]);

        // State now: full16[s0,s1,s2,s3] = A[s0,s1] * B[s2^s1, s3]  (CNOT(1,2) implicit)
        // Layer-1 Rot(0) commutes with CNOT(1,2): apply on A over s0: pairs (0,2),(1,3)
        {
            const float g00r = gates[32+0], g00i = gates[32+1];
            const float g01r = gates[32+2], g01i = gates[32+3];
            const float g10r = gates[32+4], g10i = gates[32+5];
            const float g11r = gates[32+6], g11i = gates[32+7];
#pragma unroll
            for (int j = 0; j < 2; j++) {
                const float t0r = Ar[j],   t0i = Ai[j];
                const float t1r = Ar[j+2], t1i = Ai[j+2];
                Ar[j]   = g00r*t0r - g00i*t0i + g01r*t1r - g01i*t1i;
                Ai[j]   = g00r*t0i + g00i*t0r + g01r*t1i + g01i*t1r;
                Ar[j+2] = g10r*t0r - g10i*t0i + g11r*t1r - g11i*t1i;
                Ai[j+2] = g10r*t0i + g10i*t0r + g11r*t1i + g11i*t1r;
            }
        }
        // Layer-1 Rot(3) commutes with CNOT(1,2): apply on B over s3: pairs (0,1),(2,3)
        {
            const float g00r = gates[56+0], g00i = gates[56+1];
            const float g01r = gates[56+2], g01i = gates[56+3];
            const float g10r = gates[56+4], g10i = gates[56+5];
            const float g11r = gates[56+6], g11i = gates[56+7];
#pragma unroll
            for (int k = 0; k < 2; k++) {
                const float t0r = Br[2*k],   t0i = Bi[2*k];
                const float t1r = Br[2*k+1], t1i = Bi[2*k+1];
                Br[2*k]   = g00r*t0r - g00i*t0i + g01r*t1r - g01i*t1i;
                Bi[2*k]   = g00r*t0i + g00i*t0r + g01r*t1i + g01i*t1r;
                Br[2*k+1] = g10r*t0r - g10i*t0i + g11r*t1r - g11i*t1i;
                Bi[2*k+1] = g10r*t0i + g10i*t0r + g11r*t1i + g11i*t1r;
            }
        }
        // Layer-1 Rot(2) on s2: need both branches: Bp = R2*B (s1=0), Bxp = R2*(X2 B) (s1=1)
        float Bpr[4], Bpi[4], Bxr[4], Bxi[4];
        {
            const float g00r = gates[48+0], g00i = gates[48+1];
            const float g01r = gates[48+2], g01i = gates[48+3];
            const float g10r = gates[48+4], g10i = gates[48+5];
            const float g11r = gates[48+6], g11i = gates[48+7];
#pragma unroll
            for (int s3 = 0; s3 < 2; s3++) {
                const float b0r = Br[s3],   b0i = Bi[s3];     // s2=0
                const float b1r = Br[2+s3], b1i = Bi[2+s3];   // s2=1
                // B' = R2 * B
                Bpr[s3]   = g00r*b0r - g00i*b0i + g01r*b1r - g01i*b1i;
                Bpi[s3]   = g00r*b0i + g00i*b0r + g01r*b1i + g01i*b1r;
                Bpr[2+s3] = g10r*b0r - g10i*b0i + g11r*b1r - g11i*b1i;
                Bpi[2+s3] = g10r*b0i + g10i*b0r + g11r*b1i + g11i*b1r;
                // Bx' = R2 * (rows swapped)
                Bxr[s3]   = g00r*b1r - g00i*b1i + g01r*b0r - g01i*b0i;
                Bxi[s3]   = g00r*b1i + g00i*b1r + g01r*b0i + g01i*b0r;
                Bxr[2+s3] = g10r*b1r - g10i*b1i + g11r*b0r - g11i*b0i;
                Bxi[2+s3] = g10r*b1i + g10i*b1r + g11r*b0i + g11i*b0r;
            }
        }

        // Layer-1 Rot(1) + expansion + measurement fused.
        // amp[s0,s1,s2,s3] pre-R1 = A[s0,s1] * C_{s1}[s2,s3], C_0=B', C_1=Bx'
        // Trailing CNOTs (0,1),(2,3),(1,2) are basis perms folded into signs:
        //   z0 sign: s0 ; z1: s0^s1 ; z2: s0^s1^s2 ; z3: s2^s3
        float z0 = 0.f, z1 = 0.f, z2 = 0.f, z3 = 0.f;
        {
            const float g00r = gates[40+0], g00i = gates[40+1];
            const float g01r = gates[40+2], g01i = gates[40+3];
            const float g10r = gates[40+4], g10i = gates[40+5];
            const float g11r = gates[40+6], g11i = gates[40+7];
#pragma unroll
            for (int s0 = 0; s0 < 2; s0++) {
#pragma unroll
                for (int s2 = 0; s2 < 2; s2++) {
#pragma unroll
                    for (int s3 = 0; s3 < 2; s3++) {
                        const float aA0r = Ar[s0*2+0], aA0i = Ai[s0*2+0];
                        const float aA1r = Ar[s0*2+1], aA1i = Ai[s0*2+1];
                        const float c0r = Bpr[s2*2+s3], c0i = Bpi[s2*2+s3];
                        const float c1r = Bxr[s2*2+s3], c1i = Bxi[s2*2+s3];
                        const float a0r = CMUL_R(aA0r,aA0i, c0r,c0i);
                        const float a0i = CMUL_I(aA0r,aA0i, c0r,c0i);
                        const float a1r = CMUL_R(aA1r,aA1i, c1r,c1i);
                        const float a1i = CMUL_I(aA1r,aA1i, c1r,c1i);
                        const float o0r = g00r*a0r - g00i*a0i + g01r*a1r - g01i*a1i;
                        const float o0i = g00r*a0i + g00i*a0r + g01r*a1i + g01i*a1r;
                        const float o1r = g10r*a0r - g10i*a0i + g11r*a1r - g11i*a1i;
                        const float o1i = g10r*a0i + g10i*a0r + g11r*a1i + g11i*a1r;
                        const float m0 = o0r*o0r + o0i*o0i;
                        const float m1 = o1r*o1r + o1i*o1i;
                        const float t = m0 + m1;   // s1-even
                        const float d = m0 - m1;   // s1-odd diff
                        z0 += s0 ? -t : t;
                        z1 += s0 ? -d : d;
                        z2 += (s0 ^ s2) ? -d : d;
                        z3 += (s2 ^ s3) ? -t : t;
                    }
                }
            }
        }
        feats[tid * 4 + 0] = z0;
        feats[tid * 4 + 1] = z1;
        feats[tid * 4 + 2] = z2;
        feats[tid * 4 + 3] = z3;
    }
    __syncthreads();

    // Head: logits[k] = sum_j feats[j] * head_w[k*784+j] + head_b[k]
    float acc[10];
#pragma unroll
    for (int k = 0; k < 10; k++) acc[k] = 0.0f;
    for (int j = tid; j < 784; j += 256) {
        const float f = feats[j];
#pragma unroll
        for (int k = 0; k < 10; k++) acc[k] += f * head_w[k * 784 + j];
    }
    const int lane = tid & 63, wid = tid >> 6;
#pragma unroll
    for (int k = 0; k < 10; k++) {
        float v = acc[k];
#pragma unroll
        for (int off = 32; off > 0; off >>= 1) v += __shfl_down(v, off, 64);
        if (lane == 0) red[k][wid] = v;
    }
    __syncthreads();
    if (tid < 10) {
        logits_s[tid] = red[tid][0] + red[tid][1] + red[tid][2] + red[tid][3]
                        + head_b[tid];
    }
    __syncthreads();
    if (tid == 0) {
        float mx = logits_s[0];
#pragma unroll
        for (int k = 1; k < 10; k++) mx = fmaxf(mx, logits_s[k]);
        float sum = 0.0f;
#pragma unroll
        for (int k = 0; k < 10; k++) sum += __expf(logits_s[k] - mx);
        const float lse = __logf(sum);
        float* o = out + (size_t)b * 10;
#pragma unroll
        for (int k = 0; k < 10; k++) o[k] = logits_s[k] - mx - lse;
    }
}

extern "C" void kernel_launch(void* const* d_in, const int* in_sizes, int n_in,
                              void* d_out, int out_size, void* d_ws, size_t ws_size,
                              hipStream_t stream) {
    const float* x      = (const float*)d_in[0];
    const float* params = (const float*)d_in[1];
    const float* head_w = (const float*)d_in[2];
    const float* head_b = (const float*)d_in[3];
    float* out = (float*)d_out;

    const int B = in_sizes[0] / 784;

    quanv_fused_kernel<<<B, 256, 0, stream>>>(x, params, head_w, head_b, out, B);
}

// Round 3
// 13.279 us; speedup vs baseline: 1.9912x; 1.1931x over previous
//
#include <hip/hip_runtime.h>
#include <math.h>

// Complex helpers (r,i as separate floats)
#define CMUL_R(xr,xi,yr,yi) ((xr)*(yr) - (xi)*(yi))
#define CMUL_I(xr,xi,yr,yi) ((xr)*(yi) + (xi)*(yr))

// One block per image. Threads 0..7 compute the 8 Rot gates from params
// (thread 5 also computes M = U5^dag Z U5: M00=cos(theta), M01=-sin(theta)e^{i phi}).
// Threads 0..195 each simulate one 2x2 patch via the factored product-state
// formulation; the final Rot(1) + measurement is done analytically through
// the observable M (no 16-amplitude expansion). feats -> LDS; 784x10 head +
// log_softmax in-block.
__global__ __launch_bounds__(256) void quanv_fused_kernel(
    const float* __restrict__ x,        // (B, 784)
    const float* __restrict__ params,   // (2,4,3) = 24 floats
    const float* __restrict__ head_w,   // (10, 784)
    const float* __restrict__ head_b,   // (10,)
    float* __restrict__ out,            // (B, 10)
    int B)
{
    __shared__ float gates[64];         // 8 gates x [g00r,g00i,g01r,g01i,g10r,g10i,g11r,g11i]
    __shared__ float gM[3];             // M00, M01r, M01i  (for gate 5 = layer1 wire1)
    __shared__ float feats[784];
    __shared__ float red[10][4];
    __shared__ float logits_s[10];

    const int tid = threadIdx.x;
    const int b   = blockIdx.x;

    if (tid < 8) {
        const float phi   = params[tid * 3 + 0];
        const float theta = params[tid * 3 + 1];
        const float omega = params[tid * 3 + 2];
        const float ct = __cosf(0.5f * theta),         st = __sinf(0.5f * theta);
        const float ca = __cosf(0.5f * (phi + omega)), sa = __sinf(0.5f * (phi + omega));
        const float cb = __cosf(0.5f * (phi - omega)), sb = __sinf(0.5f * (phi - omega));
        float* G = &gates[tid * 8];
        G[0] =  ca * ct;  G[1] = -sa * ct;   // g00
        G[2] = -cb * st;  G[3] = -sb * st;   // g01
        G[4] =  cb * st;  G[5] = -sb * st;   // g10
        G[6] =  ca * ct;  G[7] =  sa * ct;   // g11
        if (tid == 5) {
            // M = U^dag Z U for this gate: M00 = ct^2-st^2 = cos(theta), M11 = -M00,
            // M01 = -2 ct st e^{i phi} = -sin(theta) (cos phi + i sin phi)
            gM[0] = ct * ct - st * st;
            const float cphi = ca * cb - sa * sb;   // cos(phi)
            const float sphi = sa * cb + ca * sb;   // sin(phi)
            gM[1] = -2.0f * ct * st * cphi;
            gM[2] = -2.0f * ct * st * sphi;
        }
    }
    __syncthreads();

    if (tid < 196) {
        const int pi_ = tid / 14, pj = tid % 14;
        const float* img = x + (size_t)b * 784;
        const float2 row0 = *(const float2*)(img + (2 * pi_)     * 28 + 2 * pj);
        const float2 row1 = *(const float2*)(img + (2 * pi_ + 1) * 28 + 2 * pj);
        const float a[4] = { row0.x, row0.y, row1.x, row1.y };

        // RY(a_w) on |0>: per-wire real state (c,s)
        float cw[4], sw[4];
#pragma unroll
        for (int w = 0; w < 4; w++) {
            cw[w] = __cosf(0.5f * a[w]);
            sw[w] = __sinf(0.5f * a[w]);
        }

        // Layer-0 Rot per wire: psi_w = G * (c,s), still product state
        float p0r[4], p0i[4], p1r[4], p1i[4];
#pragma unroll
        for (int w = 0; w < 4; w++) {
            const float g00r = gates[w*8+0], g00i = gates[w*8+1];
            const float g01r = gates[w*8+2], g01i = gates[w*8+3];
            const float g10r = gates[w*8+4], g10i = gates[w*8+5];
            const float g11r = gates[w*8+6], g11i = gates[w*8+7];
            p0r[w] = fmaf(g00r, cw[w], g01r * sw[w]);
            p0i[w] = fmaf(g00i, cw[w], g01i * sw[w]);
            p1r[w] = fmaf(g10r, cw[w], g11r * sw[w]);
            p1i[w] = fmaf(g10i, cw[w], g11i * sw[w]);
        }

        // Pair A(q0,q1) = psi0 (x) psi1, with CNOT(0,1) folded (A[2]<->A[3])
        float Ar[4], Ai[4];
        Ar[0] = CMUL_R(p0r[0],p0i[0], p0r[1],p0i[1]); Ai[0] = CMUL_I(p0r[0],p0i[0], p0r[1],p0i[1]);
        Ar[1] = CMUL_R(p0r[0],p0i[0], p1r[1],p1i[1]); Ai[1] = CMUL_I(p0r[0],p0i[0], p1r[1],p1i[1]);
        Ar[2] = CMUL_R(p1r[0],p1i[0], p1r[1],p1i[1]); Ai[2] = CMUL_I(p1r[0],p1i[0], p1r[1],p1i[1]);
        Ar[3] = CMUL_R(p1r[0],p1i[0], p0r[1],p0i[1]); Ai[3] = CMUL_I(p1r[0],p1i[0], p0r[1],p0i[1]);

        // Pair B(q2,q3) = psi2 (x) psi3, with CNOT(2,3) folded (B[2]<->B[3])
        float Br[4], Bi[4];
        Br[0] = CMUL_R(p0r[2],p0i[2], p0r[3],p0i[3]); Bi[0] = CMUL_I(p0r[2],p0i[2], p0r[3],p0i[3]);
        Br[1] = CMUL_R(p0r[2],p0i[2], p1r[3],p1i[3]); Bi[1] = CMUL_I(p0r[2],p0i[2], p1r[3],p1i[3]);
        Br[2] = CMUL_R(p1r[2],p1i[2], p1r[3],p1i[3]); Bi[2] = CMUL_I(p1r[2],p1i[2], p1r[3],p1i[3]);
        Br[3] = CMUL_R(p1r[2],p1i[2], p0r[3],p0i[3]); Bi[3] = CMUL_I(p1r[2],p1i[2], p0r[3],p0i[3]);

        // Layer-1 Rot(0) on A over s0: pairs (0,2),(1,3)
        {
            const float g00r = gates[32+0], g00i = gates[32+1];
            const float g01r = gates[32+2], g01i = gates[32+3];
            const float g10r = gates[32+4], g10i = gates[32+5];
            const float g11r = gates[32+6], g11i = gates[32+7];
#pragma unroll
            for (int j = 0; j < 2; j++) {
                const float t0r = Ar[j],   t0i = Ai[j];
                const float t1r = Ar[j+2], t1i = Ai[j+2];
                Ar[j]   = g00r*t0r - g00i*t0i + g01r*t1r - g01i*t1i;
                Ai[j]   = g00r*t0i + g00i*t0r + g01r*t1i + g01i*t1r;
                Ar[j+2] = g10r*t0r - g10i*t0i + g11r*t1r - g11i*t1i;
                Ai[j+2] = g10r*t0i + g10i*t0r + g11r*t1i + g11i*t1r;
            }
        }
        // Layer-1 Rot(3) on B over s3: pairs (0,1),(2,3)
        {
            const float g00r = gates[56+0], g00i = gates[56+1];
            const float g01r = gates[56+2], g01i = gates[56+3];
            const float g10r = gates[56+4], g10i = gates[56+5];
            const float g11r = gates[56+6], g11i = gates[56+7];
#pragma unroll
            for (int k = 0; k < 2; k++) {
                const float t0r = Br[2*k],   t0i = Bi[2*k];
                const float t1r = Br[2*k+1], t1i = Bi[2*k+1];
                Br[2*k]   = g00r*t0r - g00i*t0i + g01r*t1r - g01i*t1i;
                Bi[2*k]   = g00r*t0i + g00i*t0r + g01r*t1i + g01i*t1r;
                Br[2*k+1] = g10r*t0r - g10i*t0i + g11r*t1r - g11i*t1i;
                Bi[2*k+1] = g10r*t0i + g10i*t0r + g11r*t1i + g11i*t1r;
            }
        }
        // Layer-1 Rot(2) on s2: C0 = R2*B (s1=0 branch), C1 = R2*(X2 B) (s1=1 branch)
        float Bpr[4], Bpi[4], Bxr[4], Bxi[4];
        {
            const float g00r = gates[48+0], g00i = gates[48+1];
            const float g01r = gates[48+2], g01i = gates[48+3];
            const float g10r = gates[48+4], g10i = gates[48+5];
            const float g11r = gates[48+6], g11i = gates[48+7];
#pragma unroll
            for (int s3 = 0; s3 < 2; s3++) {
                const float b0r = Br[s3],   b0i = Bi[s3];     // s2=0
                const float b1r = Br[2+s3], b1i = Bi[2+s3];   // s2=1
                Bpr[s3]   = g00r*b0r - g00i*b0i + g01r*b1r - g01i*b1i;
                Bpi[s3]   = g00r*b0i + g00i*b0r + g01r*b1i + g01i*b1r;
                Bpr[2+s3] = g10r*b0r - g10i*b0i + g11r*b1r - g11i*b1i;
                Bpi[2+s3] = g10r*b0i + g10i*b0r + g11r*b1i + g11i*b1r;
                Bxr[s3]   = g00r*b1r - g00i*b1i + g01r*b0r - g01i*b0i;
                Bxi[s3]   = g00r*b1i + g00i*b1r + g01r*b0i + g01i*b0r;
                Bxr[2+s3] = g10r*b1r - g10i*b1i + g11r*b0r - g11i*b0i;
                Bxi[2+s3] = g10r*b1i + g10i*b1r + g11r*b0i + g11i*b0r;
            }
        }

        // ---- Analytic Rot(1) + measurement ----
        // Pre-R1 state: amp[s0,s1,s2,s3] = A[s0*2+s1] * C_{s1}[s2*2+s3]
        // Signs: z0:(-1)^s0  z1:(-1)^(s0^s1)  z2:(-1)^(s0^s1^s2)  z3:(-1)^(s2^s3)
        // R1 preserves sums over s1 (z0,z3); s1-differences go through M=U^dag Z U.
        const float M00  = gM[0];
        const float M01r = gM[1], M01i = gM[2];

        // |A|^2 terms
        const float a200 = Ar[0]*Ar[0] + Ai[0]*Ai[0];
        const float a201 = Ar[1]*Ar[1] + Ai[1]*Ai[1];
        const float a210 = Ar[2]*Ar[2] + Ai[2]*Ai[2];
        const float a211 = Ar[3]*Ar[3] + Ai[3]*Ai[3];
        const float dA0 = a200 - a210, dA1 = a201 - a211;
        const float sA0 = a200 + a210, sA1 = a201 + a211;

        // |C0|^2, |C1|^2 and their signed sums over (s2,s3)
        float c20[4], c21[4];
#pragma unroll
        for (int j = 0; j < 4; j++) {
            c20[j] = Bpr[j]*Bpr[j] + Bpi[j]*Bpi[j];
            c21[j] = Bxr[j]*Bxr[j] + Bxi[j]*Bxi[j];
        }
        const float e01 = c20[0]+c20[1], e23 = c20[2]+c20[3];
        const float f01 = c20[0]-c20[1], f23 = c20[2]-c20[3];
        const float nC0 = e01+e23, uC0 = e01-e23, tC0 = f01-f23;
        const float g01_ = c21[0]+c21[1], g23 = c21[2]+c21[3];
        const float h01 = c21[0]-c21[1], h23 = c21[2]-c21[3];
        const float nC1 = g01_+g23, uC1 = g01_-g23, tC1 = h01-h23;

        // Q[j] = conj(C0[j]) * C1[j]; signed sums
        float Qr[4], Qi[4];
#pragma unroll
        for (int j = 0; j < 4; j++) {
            Qr[j] = Bpr[j]*Bxr[j] + Bpi[j]*Bxi[j];
            Qi[j] = Bpr[j]*Bxi[j] - Bpi[j]*Bxr[j];
        }
        const float SQr = (Qr[0]+Qr[1]) + (Qr[2]+Qr[3]);
        const float SQi = (Qi[0]+Qi[1]) + (Qi[2]+Qi[3]);
        const float UQr = (Qr[0]+Qr[1]) - (Qr[2]+Qr[3]);
        const float UQi = (Qi[0]+Qi[1]) - (Qi[2]+Qi[3]);

        // P_{s0} = conj(A[s0,0]) * A[s0,1];  W = M01 * (P0 - P1)
        const float P0r = Ar[0]*Ar[1] + Ai[0]*Ai[1];
        const float P0i = Ar[0]*Ai[1] - Ai[0]*Ar[1];
        const float P1r = Ar[2]*Ar[3] + Ai[2]*Ai[3];
        const float P1i = Ar[2]*Ai[3] - Ai[2]*Ar[3];
        const float dPr = P0r - P1r, dPi = P0i - P1i;
        const float Wr = M01r*dPr - M01i*dPi;
        const float Wi = M01r*dPi + M01i*dPr;

        const float T0 = dA0 * nC0, T1 = dA1 * nC1;
        const float z0 = T0 + T1;
        const float z3 = sA0 * tC0 + sA1 * tC1;
        const float z1 = M00 * (T0 - T1) + 2.0f * (Wr*SQr - Wi*SQi);
        const float z2 = M00 * (dA0*uC0 - dA1*uC1) + 2.0f * (Wr*UQr - Wi*UQi);

        feats[tid * 4 + 0] = z0;
        feats[tid * 4 + 1] = z1;
        feats[tid * 4 + 2] = z2;
        feats[tid * 4 + 3] = z3;
    }
    __syncthreads();

    // Head: logits[k] = sum_j feats[j] * head_w[k*784+j] + head_b[k]
    float acc[10];
#pragma unroll
    for (int k = 0; k < 10; k++) acc[k] = 0.0f;
#pragma unroll
    for (int i = 0; i < 3; i++) {
        const int j = tid + i * 256;
        const float f = feats[j];
#pragma unroll
        for (int k = 0; k < 10; k++) acc[k] = fmaf(f, head_w[k * 784 + j], acc[k]);
    }
    if (tid < 16) {
        const int j = tid + 768;
        const float f = feats[j];
#pragma unroll
        for (int k = 0; k < 10; k++) acc[k] = fmaf(f, head_w[k * 784 + j], acc[k]);
    }
    const int lane = tid & 63, wid = tid >> 6;
#pragma unroll
    for (int k = 0; k < 10; k++) {
        float v = acc[k];
#pragma unroll
        for (int off = 32; off > 0; off >>= 1) v += __shfl_down(v, off, 64);
        if (lane == 0) red[k][wid] = v;
    }
    __syncthreads();
    if (tid < 10) {
        logits_s[tid] = red[tid][0] + red[tid][1] + red[tid][2] + red[tid][3]
                        + head_b[tid];
    }
    __syncthreads();
    if (tid == 0) {
        float mx = logits_s[0];
#pragma unroll
        for (int k = 1; k < 10; k++) mx = fmaxf(mx, logits_s[k]);
        float sum = 0.0f;
#pragma unroll
        for (int k = 0; k < 10; k++) sum += __expf(logits_s[k] - mx);
        const float lse = __logf(sum);
        float* o = out + (size_t)b * 10;
#pragma unroll
        for (int k = 0; k < 10; k++) o[k] = logits_s[k] - mx - lse;
    }
}

extern "C" void kernel_launch(void* const* d_in, const int* in_sizes, int n_in,
                              void* d_out, int out_size, void* d_ws, size_t ws_size,
                              hipStream_t stream) {
    const float* x      = (const float*)d_in[0];
    const float* params = (const float*)d_in[1];
    const float* head_w = (const float*)d_in[2];
    const float* head_b = (const float*)d_in[3];
    float* out = (float*)d_out;

    const int B = in_sizes[0] / 784;

    quanv_fused_kernel<<<B, 256, 0, stream>>>(x, params, head_w, head_b, out, B);
}

// Round 4
// 11.319 us; speedup vs baseline: 2.3360x; 1.1732x over previous
//
#include <hip/hip_runtime.h>
#include <math.h>

// One block per image.
// Gate threads 0..3: SO(3) columns (col_x, col_z) of layer-0 Rot(w) Bloch rotation.
// Gate threads 4..7: M = Rot†·Z·Rot for layer-1 wire w: m=cosθ, w=-sinθ e^{iφ}.
// Sim threads 0..195: per-patch — per-wire Bloch vectors, then z0..z3 as closed-form
// bilinear aggregates (all layer-1 gates + trailing CNOTs pushed into observables).
// Then 784x10 head + log_softmax in-block.
__global__ __launch_bounds__(256) void quanv_fused_kernel(
    const float* __restrict__ x,        // (B, 784)
    const float* __restrict__ params,   // (2,4,3) = 24 floats
    const float* __restrict__ head_w,   // (10, 784)
    const float* __restrict__ head_b,   // (10,)
    float* __restrict__ out,            // (B, 10)
    int B)
{
    __shared__ float col[4][8];   // per layer-0 wire: cxx,cxy,cxz,-, czx,czy,czz,-
    __shared__ float Mw[4][4];    // per layer-1 wire: m, wr, wi, -
    __shared__ float feats[784];
    __shared__ float red[10][4];
    __shared__ float logits_s[10];

    const int tid = threadIdx.x;
    const int b   = blockIdx.x;

    if (tid < 4) {
        // layer-0 Rot(phi,theta,omega) = RZ(omega) RY(theta) RZ(phi) as SO(3);
        // need columns R*x_hat and R*z_hat (input Bloch = (sin a, 0, cos a)).
        const float phi   = params[tid * 3 + 0];
        const float theta = params[tid * 3 + 1];
        const float omega = params[tid * 3 + 2];
        const float cph = __cosf(phi),   sph = __sinf(phi);
        const float cth = __cosf(theta), sth = __sinf(theta);
        const float com = __cosf(omega), som = __sinf(omega);
        col[tid][0] = cth * cph * com - sph * som;   // col_x.x
        col[tid][1] = cth * cph * som + sph * com;   // col_x.y
        col[tid][2] = -sth * cph;                    // col_x.z
        col[tid][4] = sth * com;                     // col_z.x
        col[tid][5] = sth * som;                     // col_z.y
        col[tid][6] = cth;                           // col_z.z
    } else if (tid < 8) {
        const int w = tid - 4;
        const float phi   = params[12 + w * 3 + 0];
        const float theta = params[12 + w * 3 + 1];
        const float sth = __sinf(theta);
        Mw[w][0] = __cosf(theta);
        Mw[w][1] = -sth * __cosf(phi);
        Mw[w][2] = -sth * __sinf(phi);
    }
    __syncthreads();

    if (tid < 196) {
        const int pi_ = tid / 14, pj = tid % 14;
        const float* img = x + (size_t)b * 784;
        const float2 row0 = *(const float2*)(img + (2 * pi_)     * 28 + 2 * pj);
        const float2 row1 = *(const float2*)(img + (2 * pi_ + 1) * 28 + 2 * pj);
        const float a[4] = { row0.x, row0.y, row1.x, row1.y };

        // Per-wire Bloch vector after RY(a) then layer-0 Rot:
        // (x,y,z) = sin(a)*col_x + cos(a)*col_z
        // primitives: u0=(1+z)/2, u1=(1-z)/2 (pop.), q=(x+iy)/2 (coherence)
        float u0[4], u1[4], qre[4], qim[4], zb[4];
#pragma unroll
        for (int w = 0; w < 4; w++) {
            const float sa = __sinf(a[w]), ca = __cosf(a[w]);
            const float xx = fmaf(sa, col[w][0], ca * col[w][4]);
            const float yy = fmaf(sa, col[w][1], ca * col[w][5]);
            const float zz = fmaf(sa, col[w][2], ca * col[w][6]);
            zb[w]  = zz;
            u0[w]  = 0.5f + 0.5f * zz;
            u1[w]  = 0.5f - 0.5f * zz;
            qre[w] = 0.5f * xx;
            qim[w] = 0.5f * yy;
        }
        // naming: wire0 (e,q), wire1 (f,r), wire2 (g,s), wire3 (h,t)
        const float e0 = u0[0], e1 = u1[0], ze = zb[0], qr = qre[0], qi = qim[0];
        const float f0 = u0[1], f1 = u1[1], zf = zb[1], rr = qre[1], ri = qim[1];
        const float g0 = u0[2], g1 = u1[2], zg = zb[2], sr = qre[2], si = qim[2];
        const float h0 = u0[3], h1 = u1[3], zh = zb[3], tr = qre[3], ti = qim[3];

        const float m0 = Mw[0][0], w0r = Mw[0][1], w0i = Mw[0][2];
        const float m1 = Mw[1][0], w1r = Mw[1][1], w1i = Mw[1][2];
        const float m2 = Mw[2][0], w2r = Mw[2][1], w2i = Mw[2][2];
        const float m3 = Mw[3][0], w3r = Mw[3][1], w3i = Mw[3][2];

        // ---- B-side aggregates (wires 2,3) ----
        // PB = <B|X2|B>-type coherence: PB = 2*tr*s ; pb = 2*Re(PB)
        const float pb   = 4.0f * tr * sr;
        const float PBi  = 2.0f * tr * si;
        // G2 = <.|M2 (x) I|.> entries over the s1-conditioned B pair
        const float w2s_m = w2r * sr - w2i * si;
        const float w2s_p = w2r * sr + w2i * si;
        const float Ga  = fmaf(m2, zg,  4.0f * tr * w2s_m);   // G2(0,0)
        const float Gb  = fmaf(-m2, zg, 4.0f * tr * w2s_p);   // G2(1,1)
        const float Gcr = w2r;                                 // G2(0,1) real
        const float Gci = fmaf(w2i, zg, 2.0f * m2 * PBi);      // G2(0,1) imag

        // ---- z3 = aA0*G33(0,0) + aA1*G33(1,1), G33 = <.|M2 (x) M3|.> ----
        const float w3t_m = w3r * tr - w3i * ti;
        const float w3t_p = w3r * tr + w3i * ti;
        const float alpha = fmaf(m3, zh, 2.0f * w3t_m);
        const float beta  = fmaf(-m3, zh, 2.0f * w3t_p);
        const float dq    = g0 * alpha - g1 * beta;            // qu - qv
        const float Kr = w3r;
        const float Ki = fmaf(2.0f * m3, ti, w3i * zh);
        const float Tr = sr * Kr - si * Ki;
        const float Ti = sr * Ki + si * Kr;
        const float ZA = ze * zf;                              // aA0 - aA1
        const float z3 = fmaf(ZA, fmaf(m2, dq, -2.0f * w2i * Ti), 2.0f * w2r * Tr);

        // ---- z0 = m0*ze + 2*Re(w0 * PA), PA = 2*rr*q ----
        const float z0 = fmaf(m0, ze, 4.0f * rr * (w0r * qr - w0i * qi));

        // ---- z1 = <A| M0 (x) N1 |A>, N1 = [[m1, w1*pb],[conj, -m1]] ----
        const float w1r_m = w1r * rr - w1i * ri;
        const float w1r_p = w1r * rr + w1i * ri;
        const float gam1  = fmaf(m1, zf, 2.0f * pb * w1r_m);
        const float del1  = fmaf(-m1, zf, 2.0f * pb * w1r_p);
        const float diag1 = e0 * gam1 - e1 * del1;
        const float L1r = pb * w1r;
        const float L1i = fmaf(2.0f * m1, ri, pb * w1i * zf);
        const float QL1r = qr * L1r - qi * L1i;
        const float QL1i = qr * L1i + qi * L1r;
        const float z1 = fmaf(m0, diag1, 2.0f * (w0r * QL1r - w0i * QL1i));

        // ---- z2 = <A| M0 (x) N2 |A>, N2 = [[m1*Ga, w1*Gc],[conj, -m1*Gb]] ----
        const float Wgr = w1r * Gcr - w1i * Gci;
        const float Wgi = w1r * Gci + w1i * Gcr;
        const float gam2 = fmaf(m1, Ga * f0 - Gb * f1, 2.0f * (Wgr * rr - Wgi * ri));
        const float del2 = fmaf(m1, Ga * f1 - Gb * f0, 2.0f * (Wgr * rr + Wgi * ri));
        const float diag2 = e0 * gam2 - e1 * del2;
        const float L2r = fmaf(m1 * (Ga - Gb), rr, Wgr);
        const float L2i = fmaf(m1 * (Ga + Gb), ri, Wgi * zf);
        const float QL2r = qr * L2r - qi * L2i;
        const float QL2i = qr * L2i + qi * L2r;
        const float z2 = fmaf(m0, diag2, 2.0f * (w0r * QL2r - w0i * QL2i));

        feats[tid * 4 + 0] = z0;
        feats[tid * 4 + 1] = z1;
        feats[tid * 4 + 2] = z2;
        feats[tid * 4 + 3] = z3;
    }
    __syncthreads();

    // Head: logits[k] = sum_j feats[j] * head_w[k*784+j] + head_b[k]
    float acc[10];
#pragma unroll
    for (int k = 0; k < 10; k++) acc[k] = 0.0f;
#pragma unroll
    for (int i = 0; i < 3; i++) {
        const int j = tid + i * 256;
        const float f = feats[j];
#pragma unroll
        for (int k = 0; k < 10; k++) acc[k] = fmaf(f, head_w[k * 784 + j], acc[k]);
    }
    if (tid < 16) {
        const int j = tid + 768;
        const float f = feats[j];
#pragma unroll
        for (int k = 0; k < 10; k++) acc[k] = fmaf(f, head_w[k * 784 + j], acc[k]);
    }
    const int lane = tid & 63, wid = tid >> 6;
#pragma unroll
    for (int k = 0; k < 10; k++) {
        float v = acc[k];
#pragma unroll
        for (int off = 32; off > 0; off >>= 1) v += __shfl_down(v, off, 64);
        if (lane == 0) red[k][wid] = v;
    }
    __syncthreads();
    if (tid < 10) {
        logits_s[tid] = red[tid][0] + red[tid][1] + red[tid][2] + red[tid][3]
                        + head_b[tid];
    }
    __syncthreads();
    if (tid == 0) {
        float mx = logits_s[0];
#pragma unroll
        for (int k = 1; k < 10; k++) mx = fmaxf(mx, logits_s[k]);
        float sum = 0.0f;
#pragma unroll
        for (int k = 0; k < 10; k++) sum += __expf(logits_s[k] - mx);
        const float lse = __logf(sum);
        float* o = out + (size_t)b * 10;
#pragma unroll
        for (int k = 0; k < 10; k++) o[k] = logits_s[k] - mx - lse;
    }
}

extern "C" void kernel_launch(void* const* d_in, const int* in_sizes, int n_in,
                              void* d_out, int out_size, void* d_ws, size_t ws_size,
                              hipStream_t stream) {
    const float* x      = (const float*)d_in[0];
    const float* params = (const float*)d_in[1];
    const float* head_w = (const float*)d_in[2];
    const float* head_b = (const float*)d_in[3];
    float* out = (float*)d_out;

    const int B = in_sizes[0] / 784;

    quanv_fused_kernel<<<B, 256, 0, stream>>>(x, params, head_w, head_b, out, B);
}